// Round 1
// baseline (80.179 us; speedup 1.0000x reference)
//
#include <hip/hip_runtime.h>
#include <hip/hip_bf16.h>

// Sizes (fixed by the problem)
#define BATCH 8192
#define MDIM  64
#define HDIM  512
#define ODIM  64
#define IB    8
#define K2    512          // MDIM*IB, the fused contraction dim
#define NCHUNK 32          // h-chunks for precompute partials
#define HCHUNK 16          // HDIM / NCHUNK

typedef float  f32x4  __attribute__((ext_vector_type(4)));
typedef __bf16 bf16x8 __attribute__((ext_vector_type(8)));

// Cayley sign for Cl(3,0): C[a][b] -> blade a^b with this sign.
__host__ __device__ constexpr float cay(int a, int b) {
    int s = 0;
    for (int i = 0; i < 3; ++i)
        if ((b >> i) & 1) {
            int x = a >> (i + 1);
            s += (x & 1) + ((x >> 1) & 1) + ((x >> 2) & 1);
        }
    return (s & 1) ? -1.0f : 1.0f;
}

// coef[p][q] = sign(p,q) * s_{p^q}, s_k = C[k,k,0]
struct CoefT { float c[8][8]; };
constexpr CoefT make_coef() {
    CoefT t{};
    for (int p = 0; p < 8; ++p)
        for (int q = 0; q < 8; ++q)
            t.c[p][q] = cay(p, q) * cay(p ^ q, p ^ q);
    return t;
}
constexpr CoefT COEF = make_coef();

__device__ __forceinline__ unsigned short f2bf(float f) {
    __hip_bfloat16 h = __float2bfloat16(f);
    return __builtin_bit_cast(unsigned short, h);
}

// ---------------------------------------------------------------------------
// k1: partial A over h-chunk.  grid = 32 chunks x 16 om-tiles = 512 blocks.
// Block: 4 o-values x 64 m-values (256 threads). P[chunk][om*8+p] (fp32).
// ---------------------------------------------------------------------------
__global__ __launch_bounds__(256) void k_precompute(
        const float* __restrict__ Win,   // [HDIM][MDIM][IB]
        const float* __restrict__ Wout,  // [ODIM][HDIM][IB]
        float* __restrict__ P) {
    // Win slice staged with per-m stride 12 (pad 8->12): 16B-aligned, and
    // 12m % 32 tiles all 32 banks in groups of 8 lanes -> conflict-free b128.
    __shared__ float win_s[HCHUNK * 768];     // [hl][m*12+q]  48 KB
    __shared__ float wout_s[4 * HCHUNK * 8];  // [ol][hl][q]    2 KB

    const int tid   = threadIdx.x;
    const int chunk = blockIdx.x >> 4;   // 0..31
    const int omt   = blockIdx.x & 15;   // 0..15
    const int h0    = chunk * HCHUNK;

    // Stage Win rows h0..h0+15 (8192 floats, contiguous): 8 float4 / thread
    {
        const float4* src = reinterpret_cast<const float4*>(Win + h0 * (MDIM * IB));
        #pragma unroll
        for (int j = 0; j < 8; ++j) {
            int f4 = j * 256 + tid;          // 0..2047
            int hl = f4 >> 7;                // 128 float4 per h-row
            int f  = f4 & 127;
            int m  = f >> 1;
            int q4 = (f & 1) * 4;
            float4 v = src[f4];
            *reinterpret_cast<float4*>(&win_s[hl * 768 + m * 12 + q4]) = v;
        }
    }
    // Stage Wout: 4 o-rows x 16 h x 8 q = 512 floats = 128 float4
    if (tid < 128) {
        int ol = tid >> 5;
        int f  = tid & 31;
        int o  = omt * 4 + ol;
        float4 v = *reinterpret_cast<const float4*>(Wout + o * (HDIM * IB) + h0 * IB + f * 4);
        *reinterpret_cast<float4*>(&wout_s[ol * 128 + f * 4]) = v;
    }
    __syncthreads();

    const int ol = tid >> 6;   // 0..3
    const int m  = tid & 63;

    float acc[IB];
    #pragma unroll
    for (int p = 0; p < IB; ++p) acc[p] = 0.0f;

    #pragma unroll
    for (int hl = 0; hl < HCHUNK; ++hl) {
        const float* wq = &win_s[hl * 768 + m * 12];
        const float* wo = &wout_s[ol * 128 + hl * 8];
        float q[8], w[8];
        #pragma unroll
        for (int i = 0; i < 4; ++i) {
            reinterpret_cast<float4*>(q)[0] = *reinterpret_cast<const float4*>(wq);
            reinterpret_cast<float4*>(q)[1] = *reinterpret_cast<const float4*>(wq + 4);
            reinterpret_cast<float4*>(w)[0] = *reinterpret_cast<const float4*>(wo);
            reinterpret_cast<float4*>(w)[1] = *reinterpret_cast<const float4*>(wo + 4);
            break; // (loads done once; loop keeps compiler from reordering badly)
        }
        #pragma unroll
        for (int p = 0; p < IB; ++p) {
            #pragma unroll
            for (int qq = 0; qq < IB; ++qq) {
                // +-1.0f folds into the v_fma_f32 sign modifier
                acc[p] += COEF.c[p][qq] * (q[qq] * w[p ^ qq]);
            }
        }
    }

    // om = omt*256 + tid  (o = omt*4+ol, m)
    float* dst = P + chunk * 32768 + (omt * 256 + tid) * IB;
    *reinterpret_cast<float4*>(dst)     = make_float4(acc[0], acc[1], acc[2], acc[3]);
    *reinterpret_cast<float4*>(dst + 4) = make_float4(acc[4], acc[5], acc[6], acc[7]);
}

// ---------------------------------------------------------------------------
// k2: reduce 32 partials, scale by alpha, cast to bf16.  A_bf[o*512 + c].
// ---------------------------------------------------------------------------
__global__ __launch_bounds__(256) void k_reduce(
        const float* __restrict__ P, unsigned short* __restrict__ Abf, float alpha) {
    int i = blockIdx.x * 256 + threadIdx.x;   // 0..32767
    float s = 0.0f;
    #pragma unroll
    for (int ch = 0; ch < NCHUNK; ++ch) s += P[ch * 32768 + i];
    Abf[i] = f2bf(alpha * s);
}

// ---------------------------------------------------------------------------
// k3: out[b][o] = sum_c x2[b][c] * A2[o][c]  via mfma_f32_16x16x32_bf16.
// grid = 512 blocks (b-tile 16) x 256 threads (4 waves = 4 o-tiles of 16).
// x tile staged fp32->bf16 into LDS in MFMA A-fragment order:
//   xs[kstep*512 + lane*8 + j]  holds  x[b0 + (lane&15)][kstep*32 + (lane>>4)*8 + j]
// -> each wave's a-frag is one conflict-free, aligned ds_read_b128.
// ---------------------------------------------------------------------------
__global__ __launch_bounds__(256) void k_main(
        const float* __restrict__ X,              // [BATCH][K2] fp32
        const unsigned short* __restrict__ Abf,   // [ODIM][K2] bf16 bits
        float* __restrict__ Out) {                // [BATCH][ODIM]
    __shared__ unsigned short xs[16 * K2];        // 16 KB

    const int tid = threadIdx.x;
    const int b0  = blockIdx.x * 16;

    // Stage + convert: 16 rows x 512 fp32 = 2048 float4, 8 per thread.
    const float4* src = reinterpret_cast<const float4*>(X + (long)b0 * K2);
    #pragma unroll
    for (int j = 0; j < 8; ++j) {
        int f4   = j * 256 + tid;     // 0..2047
        int row  = f4 >> 7;           // 0..15
        int kc4  = f4 & 127;
        int k    = kc4 * 4;
        int kst  = k >> 5;
        int quad = (k >> 3) & 3;
        int j0   = k & 7;             // 0 or 4
        int lane = quad * 16 + row;
        float4 v = src[f4];
        ushort4 u;
        u.x = f2bf(v.x); u.y = f2bf(v.y); u.z = f2bf(v.z); u.w = f2bf(v.w);
        *reinterpret_cast<ushort4*>(&xs[kst * 512 + lane * 8 + j0]) = u;
    }
    __syncthreads();

    const int wave = tid >> 6;        // o-tile 0..3
    const int l    = tid & 63;
    const int lr   = l & 15;
    const int lq   = l >> 4;

    f32x4 acc = {0.0f, 0.0f, 0.0f, 0.0f};
    // B-frag: B[k = lq*8+j][n = lr]  = A2[o = wave*16+lr][k]
    const unsigned short* bbase = Abf + (wave * 16 + lr) * K2 + lq * 8;

    #pragma unroll
    for (int ks = 0; ks < 16; ++ks) {
        bf16x8 af = *reinterpret_cast<const bf16x8*>(&xs[ks * 512 + l * 8]);
        bf16x8 bf = *reinterpret_cast<const bf16x8*>(bbase + ks * 32);
        acc = __builtin_amdgcn_mfma_f32_16x16x32_bf16(af, bf, acc, 0, 0, 0);
    }

    // C/D: row(b) = lq*4 + r, col(o) = lr   [measured: learn_hip m89]
    float* o = Out + (long)(b0 + lq * 4) * ODIM + wave * 16 + lr;
    #pragma unroll
    for (int r = 0; r < 4; ++r) o[r * ODIM] = acc[r];
}

// ---------------------------------------------------------------------------
extern "C" void kernel_launch(void* const* d_in, const int* in_sizes, int n_in,
                              void* d_out, int out_size, void* d_ws, size_t ws_size,
                              hipStream_t stream) {
    const float* x    = (const float*)d_in[0];   // (8192, 64, 8)
    const float* Win  = (const float*)d_in[1];   // (512, 64, 8)
    const float* Wout = (const float*)d_in[2];   // (64, 512, 8)
    float* out = (float*)d_out;                  // (8192, 64)

    float* P = (float*)d_ws;                                           // 4 MB
    unsigned short* Abf =
        (unsigned short*)((char*)d_ws + (size_t)NCHUNK * 32768 * sizeof(float)); // 64 KB

    const float alpha = 0.8784233454094307f;     // 1 - 0.9^20 (closed-form relaxation)

    k_precompute<<<512, 256, 0, stream>>>(Win, Wout, P);
    k_reduce   <<<128, 256, 0, stream>>>(P, Abf, alpha);
    k_main     <<<512, 256, 0, stream>>>(x, Abf, out);
}